// Round 1
// baseline (322.072 us; speedup 1.0000x reference)
//
#include <hip/hip_runtime.h>

#define B_N 128
#define C_N 1024
#define HW_N 192
#define CI_N 512

typedef short bf16x8 __attribute__((ext_vector_type(8)));
typedef float f32x4 __attribute__((ext_vector_type(4)));
typedef unsigned short us4 __attribute__((ext_vector_type(4)));

__device__ __forceinline__ unsigned short f2bf(float f){
    unsigned int u = __builtin_bit_cast(unsigned int, f);
    u += 0x7fffu + ((u >> 16) & 1u);   // round-to-nearest-even
    return (unsigned short)(u >> 16);
}
__device__ __forceinline__ float bf2f(unsigned short h){
    unsigned int u = ((unsigned int)h) << 16;
    return __builtin_bit_cast(float, u);
}

// ---- prep: x (B,C,HW) f32  ->  xbT (B,HW,C) bf16 (transpose + convert) ----
__global__ __launch_bounds__(256) void k_prep_x(const float* __restrict__ x,
                                                unsigned short* __restrict__ xbT){
    __shared__ float tile[32][33];
    int b  = blockIdx.z;
    int c0 = blockIdx.y * 32;
    int n0 = blockIdx.x * 32;
    int tx = threadIdx.x & 31;
    int ty = threadIdx.x >> 5;   // 0..7
    const float* xp = x + (size_t)b * C_N * HW_N;
    #pragma unroll
    for (int i = 0; i < 4; ++i)
        tile[ty + 8*i][tx] = xp[(size_t)(c0 + ty + 8*i) * HW_N + n0 + tx];
    __syncthreads();
    unsigned short* op = xbT + (size_t)b * HW_N * C_N;
    #pragma unroll
    for (int i = 0; i < 4; ++i)
        op[(size_t)(n0 + ty + 8*i) * C_N + c0 + tx] = f2bf(tile[tx][ty + 8*i]);
}

// ---- prep: Wcat = [theta_w; phi_w] -> bf16 (1024x1024), bias concat -------
__global__ __launch_bounds__(256) void k_prep_w(const float* __restrict__ tw, const float* __restrict__ tb,
                                                const float* __restrict__ pw, const float* __restrict__ pb,
                                                unsigned short* __restrict__ Wc, float* __restrict__ bias){
    int i = blockIdx.x * 256 + threadIdx.x;    // over 1024*1024
    int o = i >> 10, c = i & 1023;
    float v = (o < 512) ? tw[(size_t)o * 1024 + c] : pw[(size_t)(o - 512) * 1024 + c];
    Wc[i] = f2bf(v);
    if (i < 1024) bias[i] = (i < 512) ? tb[i] : pb[i - 512];
}

// ---- GEMM1: TPt[b][n][o] = bf16( bias[o] + sum_c Wc[o][c]*xbT[b][n][c] ) --
#define G1_BM 128
#define G1_BN 64
#define LDP 40   // padded LDS row stride (elements)

__global__ __launch_bounds__(256) void k_gemm1(const unsigned short* __restrict__ Wc,
                                               const float* __restrict__ bias,
                                               const unsigned short* __restrict__ xbT,
                                               unsigned short* __restrict__ TPt){
    __shared__ __align__(16) unsigned short lA[G1_BM * LDP];
    __shared__ __align__(16) unsigned short lB[G1_BN * LDP];
    int b   = blockIdx.z;
    int mb  = blockIdx.y;      // 0..7 over o
    int nb  = blockIdx.x;      // 0..2 over n
    int tid = threadIdx.x;
    int lane = tid & 63, wave = tid >> 6;
    int wr = wave >> 1, wc = wave & 1;
    int fr = lane & 15, fg = lane >> 4;

    const unsigned short* Ag = Wc  + (size_t)(mb * G1_BM) * C_N;
    const unsigned short* Bg = xbT + ((size_t)b * HW_N + nb * G1_BN) * C_N;

    int sr = tid >> 2;          // 0..63
    int sc = (tid & 3) * 8;     // 0,8,16,24

    f32x4 acc[4][2];
    f32x4 zero = {0.f, 0.f, 0.f, 0.f};
    #pragma unroll
    for (int i = 0; i < 4; ++i)
        #pragma unroll
        for (int j = 0; j < 2; ++j)
            acc[i][j] = zero;

    for (int k0 = 0; k0 < C_N; k0 += 32){
        __syncthreads();
        *(bf16x8*)(lA + sr * LDP + sc)      = *(const bf16x8*)(Ag + (size_t)sr * C_N + k0 + sc);
        *(bf16x8*)(lA + (sr+64) * LDP + sc) = *(const bf16x8*)(Ag + (size_t)(sr+64) * C_N + k0 + sc);
        *(bf16x8*)(lB + sr * LDP + sc)      = *(const bf16x8*)(Bg + (size_t)sr * C_N + k0 + sc);
        __syncthreads();
        bf16x8 af[4], bfv[2];
        #pragma unroll
        for (int i = 0; i < 4; ++i)
            af[i] = *(const bf16x8*)(lA + (wr*64 + i*16 + fr) * LDP + fg*8);
        #pragma unroll
        for (int j = 0; j < 2; ++j)
            bfv[j] = *(const bf16x8*)(lB + (wc*32 + j*16 + fr) * LDP + fg*8);
        #pragma unroll
        for (int i = 0; i < 4; ++i)
            #pragma unroll
            for (int j = 0; j < 2; ++j)
                acc[i][j] = __builtin_amdgcn_mfma_f32_16x16x32_bf16(af[i], bfv[j], acc[i][j], 0, 0, 0);
    }

    #pragma unroll
    for (int i = 0; i < 4; ++i){
        int o0 = mb * G1_BM + wr*64 + i*16 + fg*4;
        #pragma unroll
        for (int j = 0; j < 2; ++j){
            int n = nb * G1_BN + wc*32 + j*16 + fr;
            us4 pk;
            #pragma unroll
            for (int r = 0; r < 4; ++r)
                pk[r] = f2bf(acc[i][j][r] + bias[o0 + r]);
            *(us4*)(TPt + ((size_t)b * HW_N + n) * 1024 + o0) = pk;
        }
    }
}

// ---- normalize rows of 512 in place (z-score, ddof=1, +1e-4) --------------
__global__ __launch_bounds__(256) void k_norm(unsigned short* __restrict__ TPt){
    int row  = blockIdx.x * 4 + (threadIdx.x >> 6);  // over B*HW*2
    int lane = threadIdx.x & 63;
    unsigned short* p = TPt + (size_t)(row >> 1) * 1024 + (size_t)(row & 1) * 512;
    bf16x8 v = *(const bf16x8*)(p + lane * 8);
    float f[8]; float s = 0.f;
    #pragma unroll
    for (int j = 0; j < 8; ++j){ f[j] = bf2f((unsigned short)v[j]); s += f[j]; }
    #pragma unroll
    for (int off = 32; off > 0; off >>= 1) s += __shfl_xor(s, off);
    float mean = s * (1.f / 512.f);
    float q = 0.f;
    #pragma unroll
    for (int j = 0; j < 8; ++j){ float d = f[j] - mean; q += d * d; }
    #pragma unroll
    for (int off = 32; off > 0; off >>= 1) q += __shfl_xor(q, off);
    float inv = 1.f / (sqrtf(q * (1.f / 511.f)) + 1e-4f);
    bf16x8 w;
    #pragma unroll
    for (int j = 0; j < 8; ++j) w[j] = (short)f2bf((f[j] - mean) * inv);
    *(bf16x8*)(p + lane * 8) = w;
}

// ---- GEMM2: F[b][n][m] = bf16( (1/512) sum_c ThN[b][n][c]*PhN[b][m][c] ) --
__global__ __launch_bounds__(256) void k_gemm2(const unsigned short* __restrict__ TPt,
                                               unsigned short* __restrict__ F){
    __shared__ __align__(16) unsigned short lA[64 * LDP];
    __shared__ __align__(16) unsigned short lB[64 * LDP];
    int b   = blockIdx.z;
    int tn  = blockIdx.y;   // 0..2 over n (theta positions)
    int tm  = blockIdx.x;   // 0..2 over m (phi positions)
    int tid = threadIdx.x;
    int lane = tid & 63, wave = tid >> 6;
    int wr = wave >> 1, wc = wave & 1;
    int fr = lane & 15, fg = lane >> 4;

    const unsigned short* Ag = TPt + ((size_t)b * HW_N + tn * 64) * 1024;        // theta cols 0..511
    const unsigned short* Bg = TPt + ((size_t)b * HW_N + tm * 64) * 1024 + 512;  // phi cols 512..1023

    int sr = tid >> 2, sc = (tid & 3) * 8;

    f32x4 acc[2][2];
    f32x4 zero = {0.f, 0.f, 0.f, 0.f};
    #pragma unroll
    for (int i = 0; i < 2; ++i)
        #pragma unroll
        for (int j = 0; j < 2; ++j)
            acc[i][j] = zero;

    for (int k0 = 0; k0 < 512; k0 += 32){
        __syncthreads();
        *(bf16x8*)(lA + sr * LDP + sc) = *(const bf16x8*)(Ag + (size_t)sr * 1024 + k0 + sc);
        *(bf16x8*)(lB + sr * LDP + sc) = *(const bf16x8*)(Bg + (size_t)sr * 1024 + k0 + sc);
        __syncthreads();
        bf16x8 af[2], bfv[2];
        #pragma unroll
        for (int i = 0; i < 2; ++i)
            af[i] = *(const bf16x8*)(lA + (wr*32 + i*16 + fr) * LDP + fg*8);
        #pragma unroll
        for (int j = 0; j < 2; ++j)
            bfv[j] = *(const bf16x8*)(lB + (wc*32 + j*16 + fr) * LDP + fg*8);
        #pragma unroll
        for (int i = 0; i < 2; ++i)
            #pragma unroll
            for (int j = 0; j < 2; ++j)
                acc[i][j] = __builtin_amdgcn_mfma_f32_16x16x32_bf16(af[i], bfv[j], acc[i][j], 0, 0, 0);
    }

    #pragma unroll
    for (int i = 0; i < 2; ++i)
        #pragma unroll
        for (int j = 0; j < 2; ++j)
            #pragma unroll
            for (int r = 0; r < 4; ++r){
                int n = tn*64 + wr*32 + i*16 + fg*4 + r;
                int m = tm*64 + wc*32 + j*16 + fr;
                F[((size_t)b * HW_N + n) * HW_N + m] = f2bf(acc[i][j][r] * (1.0f / 512.0f));
            }
}

// ---- mask head: conv1x1(192->64) -> BN -> ReLU -> conv1x1(64->1) -> sigmoid
__global__ __launch_bounds__(256) void k_mask(const unsigned short* __restrict__ F,
        const float* __restrict__ m1w, const float* __restrict__ m1b,
        const float* __restrict__ bng, const float* __restrict__ bnb,
        const float* __restrict__ bnm, const float* __restrict__ bnv,
        const float* __restrict__ m2w, const float* __restrict__ m2b,
        float* __restrict__ mask){
    __shared__ float w1[64][193];
    __shared__ float frow[4][200];
    __shared__ float bnsc[64], bnsh[64], w2s[64];
    int b = blockIdx.x;
    int tid = threadIdx.x, lane = tid & 63, wave = tid >> 6;
    for (int i = tid; i < 64 * 192; i += 256)
        w1[i / 192][i % 192] = m1w[i];
    if (tid < 64){
        float sc = bng[tid] * rsqrtf(bnv[tid] + 1e-5f);
        bnsc[tid] = sc;
        bnsh[tid] = bnb[tid] - bnm[tid] * sc;
        w2s[tid]  = m2w[tid];
    }
    __syncthreads();
    const unsigned short* Fb = F + (size_t)b * HW_N * HW_N;
    float mb2 = m2b[0];
    for (int n = wave; n < HW_N; n += 4){
        for (int i = lane; i < HW_N; i += 64)
            frow[wave][i] = bf2f(Fb[(size_t)n * HW_N + i]);
        __syncthreads();   // uniform: every wave runs exactly 48 iterations
        int o = lane;      // 64 output channels == 64 lanes
        float acc = m1b[o];
        for (int k = 0; k < HW_N; ++k)
            acc += w1[o][k] * frow[wave][k];
        float t = fmaxf(acc * bnsc[o] + bnsh[o], 0.f);
        float y = t * w2s[o];
        #pragma unroll
        for (int off = 32; off > 0; off >>= 1) y += __shfl_xor(y, off);
        if (lane == 0)
            mask[(size_t)b * HW_N + n] = 1.f / (1.f + __expf(-(y + mb2)));
    }
}

// ---- apply: out = x * (1 + mask) ------------------------------------------
__global__ __launch_bounds__(256) void k_apply(const float* __restrict__ x,
                                               const float* __restrict__ mask,
                                               float* __restrict__ out){
    size_t i4 = (size_t)blockIdx.x * 256 + threadIdx.x;
    size_t e  = i4 * 4;
    float4 v = ((const float4*)x)[i4];
    size_t n = e % HW_N;                        // 192 % 4 == 0: same row for all 4
    size_t b = e / ((size_t)C_N * HW_N);
    const float* mk = mask + b * HW_N + n;
    float4 o;
    o.x = v.x * (1.f + mk[0]);
    o.y = v.y * (1.f + mk[1]);
    o.z = v.z * (1.f + mk[2]);
    o.w = v.w * (1.f + mk[3]);
    ((float4*)out)[i4] = o;
}

extern "C" void kernel_launch(void* const* d_in, const int* in_sizes, int n_in,
                              void* d_out, int out_size, void* d_ws, size_t ws_size,
                              hipStream_t stream){
    (void)in_sizes; (void)n_in; (void)out_size; (void)ws_size;
    const float* x   = (const float*)d_in[0];
    const float* tw  = (const float*)d_in[1];
    const float* tb  = (const float*)d_in[2];
    const float* pw  = (const float*)d_in[3];
    const float* pb  = (const float*)d_in[4];
    const float* m1w = (const float*)d_in[5];
    const float* m1b = (const float*)d_in[6];
    const float* bng = (const float*)d_in[7];
    const float* bnb = (const float*)d_in[8];
    const float* bnm = (const float*)d_in[9];
    const float* bnv = (const float*)d_in[10];
    const float* m2w = (const float*)d_in[11];
    const float* m2b = (const float*)d_in[12];
    float* out = (float*)d_out;

    char* ws = (char*)d_ws;
    size_t off = 0;
    unsigned short* xbT = (unsigned short*)(ws + off); off += (size_t)B_N * HW_N * C_N * 2;   // 48 MB
    unsigned short* Wc  = (unsigned short*)(ws + off); off += (size_t)1024 * 1024 * 2;        // 2 MB
    float* bias         = (float*)(ws + off);          off += 4096;
    unsigned short* TPt = (unsigned short*)(ws + off); off += (size_t)B_N * HW_N * 1024 * 2;  // 48 MB
    unsigned short* F   = (unsigned short*)(ws + off); off += (size_t)B_N * HW_N * HW_N * 2;  // 9 MB
    float* mask         = (float*)(ws + off);          off += (size_t)B_N * HW_N * 4;

    k_prep_x<<<dim3(6, 32, B_N), 256, 0, stream>>>(x, xbT);
    k_prep_w<<<dim3(4096), 256, 0, stream>>>(tw, tb, pw, pb, Wc, bias);
    k_gemm1<<<dim3(3, 8, B_N), 256, 0, stream>>>(Wc, bias, xbT, TPt);
    k_norm<<<dim3(B_N * HW_N * 2 / 4), 256, 0, stream>>>(TPt);
    k_gemm2<<<dim3(3, 3, B_N), 256, 0, stream>>>(TPt, F);
    k_mask<<<dim3(B_N), 256, 0, stream>>>(F, m1w, m1b, bng, bnb, bnm, bnv, m2w, m2b, mask);
    k_apply<<<dim3(B_N * C_N * HW_N / 4 / 256), 256, 0, stream>>>(x, mask, out);
}

// Round 2
// 213.640 us; speedup vs baseline: 1.5075x; 1.5075x over previous
//
#include <hip/hip_runtime.h>

#define B_N 128
#define C_N 1024
#define HW_N 192
#define CI_N 512

typedef short bf16x8 __attribute__((ext_vector_type(8)));
typedef float f32x4 __attribute__((ext_vector_type(4)));
typedef unsigned short us4 __attribute__((ext_vector_type(4)));

__device__ __forceinline__ unsigned short f2bf(float f){
    unsigned int u = __builtin_bit_cast(unsigned int, f);
    u += 0x7fffu + ((u >> 16) & 1u);   // round-to-nearest-even
    return (unsigned short)(u >> 16);
}
__device__ __forceinline__ float bf2f(unsigned short h){
    unsigned int u = ((unsigned int)h) << 16;
    return __builtin_bit_cast(float, u);
}

// ---- prep: x (B,C,HW) f32  ->  xbT (B,HW,C) bf16 (transpose + convert) ----
__global__ __launch_bounds__(256) void k_prep_x(const float* __restrict__ x,
                                                unsigned short* __restrict__ xbT){
    __shared__ float tile[32][33];
    int b  = blockIdx.z;
    int c0 = blockIdx.y * 32;
    int n0 = blockIdx.x * 32;
    int tx = threadIdx.x & 31;
    int ty = threadIdx.x >> 5;   // 0..7
    const float* xp = x + (size_t)b * C_N * HW_N;
    #pragma unroll
    for (int i = 0; i < 4; ++i)
        tile[ty + 8*i][tx] = xp[(size_t)(c0 + ty + 8*i) * HW_N + n0 + tx];
    __syncthreads();
    unsigned short* op = xbT + (size_t)b * HW_N * C_N;
    #pragma unroll
    for (int i = 0; i < 4; ++i)
        op[(size_t)(n0 + ty + 8*i) * C_N + c0 + tx] = f2bf(tile[tx][ty + 8*i]);
}

// ---- prep: Wcat = [theta_w; phi_w] -> bf16 (1024x1024), bias concat, w1 bf16
__global__ __launch_bounds__(256) void k_prep_w(const float* __restrict__ tw, const float* __restrict__ tb,
                                                const float* __restrict__ pw, const float* __restrict__ pb,
                                                const float* __restrict__ m1w,
                                                unsigned short* __restrict__ Wc, float* __restrict__ bias,
                                                unsigned short* __restrict__ w1b){
    int i = blockIdx.x * 256 + threadIdx.x;    // over 1024*1024
    int o = i >> 10, c = i & 1023;
    float v = (o < 512) ? tw[(size_t)o * 1024 + c] : pw[(size_t)(o - 512) * 1024 + c];
    Wc[i] = f2bf(v);
    if (i < 1024) bias[i] = (i < 512) ? tb[i] : pb[i - 512];
    if (i < 64 * HW_N) w1b[i] = f2bf(m1w[i]);
}

// ---- GEMM1: TPt[b][n][o] = bf16( bias[o] + sum_c Wc[o][c]*xbT[b][n][c] ) --
#define G1_BM 128
#define G1_BN 64
#define LDP 40   // padded LDS row stride (elements)

__global__ __launch_bounds__(256) void k_gemm1(const unsigned short* __restrict__ Wc,
                                               const float* __restrict__ bias,
                                               const unsigned short* __restrict__ xbT,
                                               unsigned short* __restrict__ TPt){
    __shared__ __align__(16) unsigned short lA[G1_BM * LDP];
    __shared__ __align__(16) unsigned short lB[G1_BN * LDP];
    int b   = blockIdx.z;
    int mb  = blockIdx.y;      // 0..7 over o
    int nb  = blockIdx.x;      // 0..2 over n
    int tid = threadIdx.x;
    int lane = tid & 63, wave = tid >> 6;
    int wr = wave >> 1, wc = wave & 1;
    int fr = lane & 15, fg = lane >> 4;

    const unsigned short* Ag = Wc  + (size_t)(mb * G1_BM) * C_N;
    const unsigned short* Bg = xbT + ((size_t)b * HW_N + nb * G1_BN) * C_N;

    int sr = tid >> 2;          // 0..63
    int sc = (tid & 3) * 8;     // 0,8,16,24

    f32x4 acc[4][2];
    f32x4 zero = {0.f, 0.f, 0.f, 0.f};
    #pragma unroll
    for (int i = 0; i < 4; ++i)
        #pragma unroll
        for (int j = 0; j < 2; ++j)
            acc[i][j] = zero;

    for (int k0 = 0; k0 < C_N; k0 += 32){
        __syncthreads();
        *(bf16x8*)(lA + sr * LDP + sc)      = *(const bf16x8*)(Ag + (size_t)sr * C_N + k0 + sc);
        *(bf16x8*)(lA + (sr+64) * LDP + sc) = *(const bf16x8*)(Ag + (size_t)(sr+64) * C_N + k0 + sc);
        *(bf16x8*)(lB + sr * LDP + sc)      = *(const bf16x8*)(Bg + (size_t)sr * C_N + k0 + sc);
        __syncthreads();
        bf16x8 af[4], bfv[2];
        #pragma unroll
        for (int i = 0; i < 4; ++i)
            af[i] = *(const bf16x8*)(lA + (wr*64 + i*16 + fr) * LDP + fg*8);
        #pragma unroll
        for (int j = 0; j < 2; ++j)
            bfv[j] = *(const bf16x8*)(lB + (wc*32 + j*16 + fr) * LDP + fg*8);
        #pragma unroll
        for (int i = 0; i < 4; ++i)
            #pragma unroll
            for (int j = 0; j < 2; ++j)
                acc[i][j] = __builtin_amdgcn_mfma_f32_16x16x32_bf16(af[i], bfv[j], acc[i][j], 0, 0, 0);
    }

    #pragma unroll
    for (int i = 0; i < 4; ++i){
        int o0 = mb * G1_BM + wr*64 + i*16 + fg*4;
        #pragma unroll
        for (int j = 0; j < 2; ++j){
            int n = nb * G1_BN + wc*32 + j*16 + fr;
            us4 pk;
            #pragma unroll
            for (int r = 0; r < 4; ++r)
                pk[r] = f2bf(acc[i][j][r] + bias[o0 + r]);
            *(us4*)(TPt + ((size_t)b * HW_N + n) * 1024 + o0) = pk;
        }
    }
}

// ---- normalize rows of 512 in place (z-score, ddof=1, +1e-4) --------------
__global__ __launch_bounds__(256) void k_norm(unsigned short* __restrict__ TPt){
    int row  = blockIdx.x * 4 + (threadIdx.x >> 6);  // over B*HW*2
    int lane = threadIdx.x & 63;
    unsigned short* p = TPt + (size_t)(row >> 1) * 1024 + (size_t)(row & 1) * 512;
    bf16x8 v = *(const bf16x8*)(p + lane * 8);
    float f[8]; float s = 0.f;
    #pragma unroll
    for (int j = 0; j < 8; ++j){ f[j] = bf2f((unsigned short)v[j]); s += f[j]; }
    #pragma unroll
    for (int off = 32; off > 0; off >>= 1) s += __shfl_xor(s, off);
    float mean = s * (1.f / 512.f);
    float q = 0.f;
    #pragma unroll
    for (int j = 0; j < 8; ++j){ float d = f[j] - mean; q += d * d; }
    #pragma unroll
    for (int off = 32; off > 0; off >>= 1) q += __shfl_xor(q, off);
    float inv = 1.f / (sqrtf(q * (1.f / 511.f)) + 1e-4f);
    bf16x8 w;
    #pragma unroll
    for (int j = 0; j < 8; ++j) w[j] = (short)f2bf((f[j] - mean) * inv);
    *(bf16x8*)(p + lane * 8) = w;
}

// ---- GEMM2: F[b][n][m] = bf16( (1/512) sum_c ThN[b][n][c]*PhN[b][m][c] ) --
__global__ __launch_bounds__(256) void k_gemm2(const unsigned short* __restrict__ TPt,
                                               unsigned short* __restrict__ F){
    __shared__ __align__(16) unsigned short lA[64 * LDP];
    __shared__ __align__(16) unsigned short lB[64 * LDP];
    int b   = blockIdx.z;
    int tn  = blockIdx.y;   // 0..2 over n (theta positions)
    int tm  = blockIdx.x;   // 0..2 over m (phi positions)
    int tid = threadIdx.x;
    int lane = tid & 63, wave = tid >> 6;
    int wr = wave >> 1, wc = wave & 1;
    int fr = lane & 15, fg = lane >> 4;

    const unsigned short* Ag = TPt + ((size_t)b * HW_N + tn * 64) * 1024;        // theta cols 0..511
    const unsigned short* Bg = TPt + ((size_t)b * HW_N + tm * 64) * 1024 + 512;  // phi cols 512..1023

    int sr = tid >> 2, sc = (tid & 3) * 8;

    f32x4 acc[2][2];
    f32x4 zero = {0.f, 0.f, 0.f, 0.f};
    #pragma unroll
    for (int i = 0; i < 2; ++i)
        #pragma unroll
        for (int j = 0; j < 2; ++j)
            acc[i][j] = zero;

    for (int k0 = 0; k0 < 512; k0 += 32){
        __syncthreads();
        *(bf16x8*)(lA + sr * LDP + sc) = *(const bf16x8*)(Ag + (size_t)sr * 1024 + k0 + sc);
        *(bf16x8*)(lB + sr * LDP + sc) = *(const bf16x8*)(Bg + (size_t)sr * 1024 + k0 + sc);
        __syncthreads();
        bf16x8 af[2], bfv[2];
        #pragma unroll
        for (int i = 0; i < 2; ++i)
            af[i] = *(const bf16x8*)(lA + (wr*32 + i*16 + fr) * LDP + fg*8);
        #pragma unroll
        for (int j = 0; j < 2; ++j)
            bfv[j] = *(const bf16x8*)(lB + (wc*32 + j*16 + fr) * LDP + fg*8);
        #pragma unroll
        for (int i = 0; i < 2; ++i)
            #pragma unroll
            for (int j = 0; j < 2; ++j)
                acc[i][j] = __builtin_amdgcn_mfma_f32_16x16x32_bf16(af[i], bfv[j], acc[i][j], 0, 0, 0);
    }

    #pragma unroll
    for (int i = 0; i < 2; ++i)
        #pragma unroll
        for (int j = 0; j < 2; ++j)
            #pragma unroll
            for (int r = 0; r < 4; ++r){
                int n = tn*64 + wr*32 + i*16 + fg*4 + r;
                int m = tm*64 + wc*32 + j*16 + fr;
                F[((size_t)b * HW_N + n) * HW_N + m] = f2bf(acc[i][j][r] * (1.0f / 512.0f));
            }
}

// ---- mask head via MFMA: rows = B*HW flat, y[row] = sigmoid(w2·relu(BN(w1·Frow + m1b)))
// one wave = 16 rows x 64 o's, K=192 in 6 MFMA steps; block = 4 waves = 64 rows
__global__ __launch_bounds__(256) void k_mask2(const unsigned short* __restrict__ F,
        const unsigned short* __restrict__ w1b, const float* __restrict__ m1b,
        const float* __restrict__ bng, const float* __restrict__ bnb,
        const float* __restrict__ bnm, const float* __restrict__ bnv,
        const float* __restrict__ m2w, const float* __restrict__ m2b,
        float* __restrict__ mask){
    int tid = threadIdx.x, lane = tid & 63, wave = tid >> 6;
    int fr = lane & 15, fg = lane >> 4;
    int row0 = blockIdx.x * 64 + wave * 16;        // 16 rows per wave
    const unsigned short* Ag = F + (size_t)row0 * HW_N;

    f32x4 acc[4];
    f32x4 zero = {0.f, 0.f, 0.f, 0.f};
    #pragma unroll
    for (int j = 0; j < 4; ++j) acc[j] = zero;

    #pragma unroll
    for (int kk = 0; kk < 6; ++kk){
        bf16x8 af = *(const bf16x8*)(Ag + (size_t)fr * HW_N + kk * 32 + fg * 8);
        #pragma unroll
        for (int j = 0; j < 4; ++j){
            bf16x8 bfv = *(const bf16x8*)(w1b + (size_t)(j * 16 + fr) * HW_N + kk * 32 + fg * 8);
            acc[j] = __builtin_amdgcn_mfma_f32_16x16x32_bf16(af, bfv, acc[j], 0, 0, 0);
        }
    }

    // per-lane params for its 4 o's (o = j*16 + fr)
    float sc[4], sh[4], bb[4], w2v[4];
    #pragma unroll
    for (int j = 0; j < 4; ++j){
        int o = j * 16 + fr;
        float s = bng[o] * rsqrtf(bnv[o] + 1e-5f);
        sc[j] = s;
        sh[j] = bnb[o] - bnm[o] * s;
        bb[j] = m1b[o];
        w2v[j] = m2w[o];
    }
    float mb2 = m2b[0];

    #pragma unroll
    for (int r = 0; r < 4; ++r){
        float y = 0.f;
        #pragma unroll
        for (int j = 0; j < 4; ++j){
            float t = fmaxf((acc[j][r] + bb[j]) * sc[j] + sh[j], 0.f);
            y += t * w2v[j];
        }
        // reduce over the 16 lanes sharing fg (o across fr)
        y += __shfl_xor(y, 1);
        y += __shfl_xor(y, 2);
        y += __shfl_xor(y, 4);
        y += __shfl_xor(y, 8);
        if (fr == 0)
            mask[row0 + fg * 4 + r] = 1.f / (1.f + __expf(-(y + mb2)));
    }
}

// ---- apply: out = x * (1 + mask) ------------------------------------------
__global__ __launch_bounds__(256) void k_apply(const float* __restrict__ x,
                                               const float* __restrict__ mask,
                                               float* __restrict__ out){
    size_t i4 = (size_t)blockIdx.x * 256 + threadIdx.x;
    size_t e  = i4 * 4;
    float4 v = ((const float4*)x)[i4];
    size_t n = e % HW_N;                        // 192 % 4 == 0: same row for all 4
    size_t b = e / ((size_t)C_N * HW_N);
    const float* mk = mask + b * HW_N + n;
    float4 o;
    o.x = v.x * (1.f + mk[0]);
    o.y = v.y * (1.f + mk[1]);
    o.z = v.z * (1.f + mk[2]);
    o.w = v.w * (1.f + mk[3]);
    ((float4*)out)[i4] = o;
}

extern "C" void kernel_launch(void* const* d_in, const int* in_sizes, int n_in,
                              void* d_out, int out_size, void* d_ws, size_t ws_size,
                              hipStream_t stream){
    (void)in_sizes; (void)n_in; (void)out_size; (void)ws_size;
    const float* x   = (const float*)d_in[0];
    const float* tw  = (const float*)d_in[1];
    const float* tb  = (const float*)d_in[2];
    const float* pw  = (const float*)d_in[3];
    const float* pb  = (const float*)d_in[4];
    const float* m1w = (const float*)d_in[5];
    const float* m1b = (const float*)d_in[6];
    const float* bng = (const float*)d_in[7];
    const float* bnb = (const float*)d_in[8];
    const float* bnm = (const float*)d_in[9];
    const float* bnv = (const float*)d_in[10];
    const float* m2w = (const float*)d_in[11];
    const float* m2b = (const float*)d_in[12];
    float* out = (float*)d_out;

    char* ws = (char*)d_ws;
    size_t off = 0;
    unsigned short* xbT = (unsigned short*)(ws + off); off += (size_t)B_N * HW_N * C_N * 2;   // 48 MB
    unsigned short* Wc  = (unsigned short*)(ws + off); off += (size_t)1024 * 1024 * 2;        // 2 MB
    float* bias         = (float*)(ws + off);          off += 4096;
    unsigned short* TPt = (unsigned short*)(ws + off); off += (size_t)B_N * HW_N * 1024 * 2;  // 48 MB
    unsigned short* F   = (unsigned short*)(ws + off); off += (size_t)B_N * HW_N * HW_N * 2;  // 9 MB
    float* mask         = (float*)(ws + off);          off += (size_t)B_N * HW_N * 4;
    unsigned short* w1b = (unsigned short*)(ws + off); off += (size_t)64 * HW_N * 2;

    k_prep_x<<<dim3(6, 32, B_N), 256, 0, stream>>>(x, xbT);
    k_prep_w<<<dim3(4096), 256, 0, stream>>>(tw, tb, pw, pb, m1w, Wc, bias, w1b);
    k_gemm1<<<dim3(3, 8, B_N), 256, 0, stream>>>(Wc, bias, xbT, TPt);
    k_norm<<<dim3(B_N * HW_N * 2 / 4), 256, 0, stream>>>(TPt);
    k_gemm2<<<dim3(3, 3, B_N), 256, 0, stream>>>(TPt, F);
    k_mask2<<<dim3(B_N * HW_N / 64), 256, 0, stream>>>(F, w1b, m1b, bng, bnb, bnm, bnv, m2w, m2b, mask);
    k_apply<<<dim3(B_N * C_N * HW_N / 4 / 256), 256, 0, stream>>>(x, mask, out);
}

// Round 3
// 191.831 us; speedup vs baseline: 1.6789x; 1.1137x over previous
//
#include <hip/hip_runtime.h>

#define B_N 128
#define C_N 1024
#define HW_N 192
#define CI_N 512
#define MROWS (B_N * HW_N)   // 24576 flat rows

typedef short bf16x8 __attribute__((ext_vector_type(8)));
typedef float f32x4 __attribute__((ext_vector_type(4)));
typedef unsigned short us4 __attribute__((ext_vector_type(4)));

__device__ __forceinline__ unsigned short f2bf(float f){
    unsigned int u = __builtin_bit_cast(unsigned int, f);
    u += 0x7fffu + ((u >> 16) & 1u);   // round-to-nearest-even
    return (unsigned short)(u >> 16);
}
__device__ __forceinline__ float bf2f(unsigned short h){
    unsigned int u = ((unsigned int)h) << 16;
    return __builtin_bit_cast(float, u);
}
__device__ __forceinline__ void gload_lds16(const void* g, void* l){
    __builtin_amdgcn_global_load_lds(
        (const __attribute__((address_space(1))) unsigned int*)g,
        (__attribute__((address_space(3))) unsigned int*)l, 16, 0, 0);
}

// ---- prep: x (B,C,HW) f32  ->  xbT (B,HW,C) bf16 (transpose + convert) ----
__global__ __launch_bounds__(256) void k_prep_x(const float* __restrict__ x,
                                                unsigned short* __restrict__ xbT){
    __shared__ float tile[32][33];
    int b  = blockIdx.z;
    int c0 = blockIdx.y * 32;
    int n0 = blockIdx.x * 32;
    int tx = threadIdx.x & 31;
    int ty = threadIdx.x >> 5;   // 0..7
    const float* xp = x + (size_t)b * C_N * HW_N;
    #pragma unroll
    for (int i = 0; i < 4; ++i)
        tile[ty + 8*i][tx] = xp[(size_t)(c0 + ty + 8*i) * HW_N + n0 + tx];
    __syncthreads();
    unsigned short* op = xbT + (size_t)b * HW_N * C_N;
    #pragma unroll
    for (int i = 0; i < 4; ++i)
        op[(size_t)(n0 + ty + 8*i) * C_N + c0 + tx] = f2bf(tile[tx][ty + 8*i]);
}

// ---- prep: Wcat = [theta_w; phi_w] -> bf16 (1024x1024), bias concat, w1 bf16
__global__ __launch_bounds__(256) void k_prep_w(const float* __restrict__ tw, const float* __restrict__ tb,
                                                const float* __restrict__ pw, const float* __restrict__ pb,
                                                const float* __restrict__ m1w,
                                                unsigned short* __restrict__ Wc, float* __restrict__ bias,
                                                unsigned short* __restrict__ w1b){
    int i = blockIdx.x * 256 + threadIdx.x;    // over 1024*1024
    int o = i >> 10, c = i & 1023;
    float v = (o < 512) ? tw[(size_t)o * 1024 + c] : pw[(size_t)(o - 512) * 1024 + c];
    Wc[i] = f2bf(v);
    if (i < 1024) bias[i] = (i < 512) ? tb[i] : pb[i - 512];
    if (i < 64 * HW_N) w1b[i] = f2bf(m1w[i]);
}

// ---- GEMM1 (m97-style): TPt[n][o] = bias[o] + sum_c Wc[o][c]*xbT[n][c] ----
// One flat GEMM: M=24576 (n rows of xbT), N=1024 (o rows of Wc), K=1024.
// BM=BN=128, BK=32. grid 1536: o-tile = bid&7 (XCD-aligned), n-tile = bid>>3.
// Staging via global_load_lds w16 into LINEAR LDS; XOR swizzle carried on the
// GLOBAL source address + on the ds_read side (rule 21: both-sides-or-neither).
// Epilogue also emits per-row (sum, sumsq) partials over this block's 64-col
// chunks for the fused channel z-score (replaces k_norm).
__global__ __launch_bounds__(256) void k_gemm1(const unsigned short* __restrict__ Wc,
                                               const float* __restrict__ bias,
                                               const unsigned short* __restrict__ xbT,
                                               unsigned short* __restrict__ TPt,
                                               float2* __restrict__ part){
    __shared__ __align__(16) unsigned short lW[128 * 32];  // rows = o, 64B/row
    __shared__ __align__(16) unsigned short lX[128 * 32];  // rows = n
    int bid = blockIdx.x;
    int nb = bid & 7;        // o-tile (0..7)  -> pins Wc panel to one XCD L2
    int mb = bid >> 3;       // n-tile (0..191)
    int tid = threadIdx.x, lane = tid & 63, wave = tid >> 6;
    int wr = wave >> 1, wc = wave & 1;
    int fr = lane & 15, fg = lane >> 4;

    const unsigned short* Wg = Wc  + (size_t)(nb * 128) * C_N;
    const unsigned short* Xg = xbT + (size_t)(mb * 128) * C_N;

    // staging geometry: issue covers 64 rows; thread t -> row wave*16+(lane>>2), 16B unit lane&3
    int srow  = wave * 16 + (lane >> 2);
    int gu    = ((lane & 3) ^ ((srow >> 1) & 3)) * 8;   // pre-swizzled global col (elems)
    char* dW0 = (char*)lW + tid * 16;
    char* dW1 = (char*)lW + 4096 + tid * 16;
    char* dX0 = (char*)lX + tid * 16;
    char* dX1 = (char*)lX + 4096 + tid * 16;

    f32x4 acc[4][4];
    f32x4 zero = {0.f, 0.f, 0.f, 0.f};
    #pragma unroll
    for (int i = 0; i < 4; ++i)
        #pragma unroll
        for (int j = 0; j < 4; ++j)
            acc[i][j] = zero;

    for (int k0 = 0; k0 < C_N; k0 += 32){
        __syncthreads();
        gload_lds16(Wg + (size_t)srow * C_N + k0 + gu, dW0);
        gload_lds16(Wg + (size_t)(srow + 64) * C_N + k0 + gu, dW1);
        gload_lds16(Xg + (size_t)srow * C_N + k0 + gu, dX0);
        gload_lds16(Xg + (size_t)(srow + 64) * C_N + k0 + gu, dX1);
        __syncthreads();   // compiler drains vmcnt(0) here (m97 structure)

        bf16x8 wf[4], xf[4];
        #pragma unroll
        for (int j = 0; j < 4; ++j){
            int row = wc * 64 + j * 16 + fr;
            wf[j] = *(const bf16x8*)((char*)lW + row * 64 + ((fg ^ ((row >> 1) & 3)) * 16));
        }
        #pragma unroll
        for (int i = 0; i < 4; ++i){
            int row = wr * 64 + i * 16 + fr;
            xf[i] = *(const bf16x8*)((char*)lX + row * 64 + ((fg ^ ((row >> 1) & 3)) * 16));
        }
        #pragma unroll
        for (int i = 0; i < 4; ++i)
            #pragma unroll
            for (int j = 0; j < 4; ++j)
                acc[i][j] = __builtin_amdgcn_mfma_f32_16x16x32_bf16(wf[j], xf[i], acc[i][j], 0, 0, 0);
    }

    // epilogue: D[row=o (fg*4+r within frag j), col=n (fr within frag i)]
    float s[4] = {0.f,0.f,0.f,0.f}, q[4] = {0.f,0.f,0.f,0.f};
    #pragma unroll
    for (int i = 0; i < 4; ++i){
        int n = mb * 128 + wr * 64 + i * 16 + fr;
        #pragma unroll
        for (int j = 0; j < 4; ++j){
            int o0 = nb * 128 + wc * 64 + j * 16 + fg * 4;
            float4 b4 = *(const float4*)(bias + o0);
            float v0 = acc[i][j][0] + b4.x;
            float v1 = acc[i][j][1] + b4.y;
            float v2 = acc[i][j][2] + b4.z;
            float v3 = acc[i][j][3] + b4.w;
            s[i] += v0 + v1 + v2 + v3;
            q[i] += v0*v0 + v1*v1 + v2*v2 + v3*v3;
            us4 pk;
            pk[0] = f2bf(v0); pk[1] = f2bf(v1); pk[2] = f2bf(v2); pk[3] = f2bf(v3);
            *(us4*)(TPt + (size_t)n * 1024 + o0) = pk;
        }
    }
    // reduce across the 4 fg groups (lanes fr, fr+16, fr+32, fr+48)
    #pragma unroll
    for (int i = 0; i < 4; ++i){
        s[i] += __shfl_xor(s[i], 16); s[i] += __shfl_xor(s[i], 32);
        q[i] += __shfl_xor(q[i], 16); q[i] += __shfl_xor(q[i], 32);
    }
    if (lane < 16){   // fg == 0
        int chunk = nb * 2 + wc;   // 64-col chunk index (0..15)
        #pragma unroll
        for (int i = 0; i < 4; ++i){
            int n = mb * 128 + wr * 64 + i * 16 + fr;
            part[(size_t)n * 16 + chunk] = make_float2(s[i], q[i]);
        }
    }
}

// ---- fold partials -> per-(row, half) mean & 1/(std+eps), ddof=1 ----------
__global__ __launch_bounds__(256) void k_stats(const float2* __restrict__ part,
                                               float2* __restrict__ stats){
    int idx = blockIdx.x * 256 + threadIdx.x;   // over MROWS*2, exact
    int n = idx >> 1, h = idx & 1;
    const float2* p = part + (size_t)n * 16 + h * 8;
    float S = 0.f, Q = 0.f;
    #pragma unroll
    for (int k = 0; k < 8; ++k){ float2 v = p[k]; S += v.x; Q += v.y; }
    float mean = S * (1.f / 512.f);
    float var  = (Q - 512.f * mean * mean) * (1.f / 511.f);
    float inv  = 1.f / (sqrtf(fmaxf(var, 0.f)) + 1e-4f);
    stats[idx] = make_float2(mean, inv);
}

// ---- GEMM2 with fused z-score: F[b][n][m] = (ThN[n]·PhN[m])/512 -----------
// Reg-staged LDS (normalize on the fly), XOR-swizzled write+read.
__global__ __launch_bounds__(256) void k_gemm2(const unsigned short* __restrict__ TPt,
                                               const float2* __restrict__ stats,
                                               unsigned short* __restrict__ F){
    __shared__ __align__(16) unsigned short lT[64 * 32];  // theta rows (n)
    __shared__ __align__(16) unsigned short lP[64 * 32];  // phi rows (m)
    int b   = blockIdx.z;
    int tn  = blockIdx.y;   // theta 64-row panel
    int tm  = blockIdx.x;   // phi 64-row panel
    int tid = threadIdx.x, lane = tid & 63, wave = tid >> 6;
    int wr = wave >> 1, wc = wave & 1;
    int fr = lane & 15, fg = lane >> 4;

    int sr = tid >> 2;                       // 0..63 staged row
    int su = tid & 3;                        // 16B unit
    int swu = (su ^ ((sr >> 1) & 3)) * 16;   // swizzled LDS byte offset of unit
    int gn = b * HW_N + tn * 64 + sr;        // theta global row
    int gm = b * HW_N + tm * 64 + sr;        // phi global row
    float2 stT = stats[(size_t)gn * 2 + 0];
    float2 stP = stats[(size_t)gm * 2 + 1];

    f32x4 acc[2][2];
    f32x4 zero = {0.f, 0.f, 0.f, 0.f};
    #pragma unroll
    for (int i = 0; i < 2; ++i)
        #pragma unroll
        for (int j = 0; j < 2; ++j)
            acc[i][j] = zero;

    for (int k0 = 0; k0 < CI_N; k0 += 32){
        bf16x8 vt = *(const bf16x8*)(TPt + (size_t)gn * 1024 + k0 + su * 8);
        bf16x8 vp = *(const bf16x8*)(TPt + (size_t)gm * 1024 + 512 + k0 + su * 8);
        bf16x8 nt, np;
        #pragma unroll
        for (int e = 0; e < 8; ++e){
            nt[e] = (short)f2bf((bf2f((unsigned short)vt[e]) - stT.x) * stT.y);
            np[e] = (short)f2bf((bf2f((unsigned short)vp[e]) - stP.x) * stP.y);
        }
        __syncthreads();
        *(bf16x8*)((char*)lT + sr * 64 + swu) = nt;
        *(bf16x8*)((char*)lP + sr * 64 + swu) = np;
        __syncthreads();

        bf16x8 tf[2], pf[2];
        #pragma unroll
        for (int i = 0; i < 2; ++i){
            int row = wr * 32 + i * 16 + fr;
            tf[i] = *(const bf16x8*)((char*)lT + row * 64 + ((fg ^ ((row >> 1) & 3)) * 16));
        }
        #pragma unroll
        for (int j = 0; j < 2; ++j){
            int row = wc * 32 + j * 16 + fr;
            pf[j] = *(const bf16x8*)((char*)lP + row * 64 + ((fg ^ ((row >> 1) & 3)) * 16));
        }
        #pragma unroll
        for (int i = 0; i < 2; ++i)
            #pragma unroll
            for (int j = 0; j < 2; ++j)
                acc[i][j] = __builtin_amdgcn_mfma_f32_16x16x32_bf16(pf[j], tf[i], acc[i][j], 0, 0, 0);
    }

    // D[row=m (fg*4+r within frag j), col=n (fr within frag i)] -> F[n][m] us4
    #pragma unroll
    for (int i = 0; i < 2; ++i){
        int n = tn * 64 + wr * 32 + i * 16 + fr;
        #pragma unroll
        for (int j = 0; j < 2; ++j){
            int m0 = tm * 64 + wc * 32 + j * 16 + fg * 4;
            us4 pk;
            #pragma unroll
            for (int r = 0; r < 4; ++r)
                pk[r] = f2bf(acc[i][j][r] * (1.0f / 512.0f));
            *(us4*)(F + ((size_t)b * HW_N + n) * HW_N + m0) = pk;
        }
    }
}

// ---- mask head via MFMA: y[row] = sigmoid(w2·relu(BN(w1·Frow + m1b))) -----
__global__ __launch_bounds__(256) void k_mask2(const unsigned short* __restrict__ F,
        const unsigned short* __restrict__ w1b, const float* __restrict__ m1b,
        const float* __restrict__ bng, const float* __restrict__ bnb,
        const float* __restrict__ bnm, const float* __restrict__ bnv,
        const float* __restrict__ m2w, const float* __restrict__ m2b,
        float* __restrict__ mask){
    int tid = threadIdx.x, lane = tid & 63, wave = tid >> 6;
    int fr = lane & 15, fg = lane >> 4;
    int row0 = blockIdx.x * 64 + wave * 16;        // 16 rows per wave
    const unsigned short* Ag = F + (size_t)row0 * HW_N;

    f32x4 acc[4];
    f32x4 zero = {0.f, 0.f, 0.f, 0.f};
    #pragma unroll
    for (int j = 0; j < 4; ++j) acc[j] = zero;

    #pragma unroll
    for (int kk = 0; kk < 6; ++kk){
        bf16x8 af = *(const bf16x8*)(Ag + (size_t)fr * HW_N + kk * 32 + fg * 8);
        #pragma unroll
        for (int j = 0; j < 4; ++j){
            bf16x8 bfv = *(const bf16x8*)(w1b + (size_t)(j * 16 + fr) * HW_N + kk * 32 + fg * 8);
            acc[j] = __builtin_amdgcn_mfma_f32_16x16x32_bf16(af, bfv, acc[j], 0, 0, 0);
        }
    }

    float sc[4], sh[4], bb[4], w2v[4];
    #pragma unroll
    for (int j = 0; j < 4; ++j){
        int o = j * 16 + fr;
        float s = bng[o] * rsqrtf(bnv[o] + 1e-5f);
        sc[j] = s;
        sh[j] = bnb[o] - bnm[o] * s;
        bb[j] = m1b[o];
        w2v[j] = m2w[o];
    }
    float mb2 = m2b[0];

    #pragma unroll
    for (int r = 0; r < 4; ++r){
        float y = 0.f;
        #pragma unroll
        for (int j = 0; j < 4; ++j){
            float t = fmaxf((acc[j][r] + bb[j]) * sc[j] + sh[j], 0.f);
            y += t * w2v[j];
        }
        y += __shfl_xor(y, 1);
        y += __shfl_xor(y, 2);
        y += __shfl_xor(y, 4);
        y += __shfl_xor(y, 8);
        if (fr == 0)
            mask[row0 + fg * 4 + r] = 1.f / (1.f + __expf(-(y + mb2)));
    }
}

// ---- apply: out = x * (1 + mask) ------------------------------------------
__global__ __launch_bounds__(256) void k_apply(const float* __restrict__ x,
                                               const float* __restrict__ mask,
                                               float* __restrict__ out){
    size_t i4 = (size_t)blockIdx.x * 256 + threadIdx.x;
    size_t e  = i4 * 4;
    float4 v = ((const float4*)x)[i4];
    size_t n = e % HW_N;                        // 192 % 4 == 0: same row for all 4
    size_t b = e / ((size_t)C_N * HW_N);
    const float* mk = mask + b * HW_N + n;
    float4 o;
    o.x = v.x * (1.f + mk[0]);
    o.y = v.y * (1.f + mk[1]);
    o.z = v.z * (1.f + mk[2]);
    o.w = v.w * (1.f + mk[3]);
    ((float4*)out)[i4] = o;
}

extern "C" void kernel_launch(void* const* d_in, const int* in_sizes, int n_in,
                              void* d_out, int out_size, void* d_ws, size_t ws_size,
                              hipStream_t stream){
    (void)in_sizes; (void)n_in; (void)out_size; (void)ws_size;
    const float* x   = (const float*)d_in[0];
    const float* tw  = (const float*)d_in[1];
    const float* tb  = (const float*)d_in[2];
    const float* pw  = (const float*)d_in[3];
    const float* pb  = (const float*)d_in[4];
    const float* m1w = (const float*)d_in[5];
    const float* m1b = (const float*)d_in[6];
    const float* bng = (const float*)d_in[7];
    const float* bnb = (const float*)d_in[8];
    const float* bnm = (const float*)d_in[9];
    const float* bnv = (const float*)d_in[10];
    const float* m2w = (const float*)d_in[11];
    const float* m2b = (const float*)d_in[12];
    float* out = (float*)d_out;

    char* ws = (char*)d_ws;
    size_t off = 0;
    unsigned short* xbT = (unsigned short*)(ws + off); off += (size_t)MROWS * C_N * 2;        // 48 MB
    unsigned short* Wc  = (unsigned short*)(ws + off); off += (size_t)1024 * 1024 * 2;        // 2 MB
    float* bias         = (float*)(ws + off);          off += 4096;
    unsigned short* TPt = (unsigned short*)(ws + off); off += (size_t)MROWS * 1024 * 2;       // 48 MB
    unsigned short* F   = (unsigned short*)(ws + off); off += (size_t)MROWS * HW_N * 2;       // 9 MB
    float* mask         = (float*)(ws + off);          off += (size_t)MROWS * 4;
    unsigned short* w1b = (unsigned short*)(ws + off); off += (size_t)64 * HW_N * 2;
    off = (off + 255) & ~(size_t)255;
    float2* part        = (float2*)(ws + off);         off += (size_t)MROWS * 16 * 8;         // 3 MB
    float2* stats       = (float2*)(ws + off);         off += (size_t)MROWS * 2 * 8;          // 0.4 MB

    k_prep_x<<<dim3(6, 32, B_N), 256, 0, stream>>>(x, xbT);
    k_prep_w<<<dim3(4096), 256, 0, stream>>>(tw, tb, pw, pb, m1w, Wc, bias, w1b);
    k_gemm1<<<dim3(1536), 256, 0, stream>>>(Wc, bias, xbT, TPt, part);
    k_stats<<<dim3(MROWS * 2 / 256), 256, 0, stream>>>(part, stats);
    k_gemm2<<<dim3(3, 3, B_N), 256, 0, stream>>>(TPt, stats, F);
    k_mask2<<<dim3(MROWS / 64), 256, 0, stream>>>(F, w1b, m1b, bng, bnb, bnm, bnv, m2w, m2b, mask);
    k_apply<<<dim3(MROWS * C_N / 4 / 256), 256, 0, stream>>>(x, mask, out);
}

// Round 4
// 175.640 us; speedup vs baseline: 1.8337x; 1.0922x over previous
//
#include <hip/hip_runtime.h>

#define B_N 128
#define C_N 1024
#define HW_N 192
#define CI_N 512
#define MROWS (B_N * HW_N)   // 24576 flat rows

typedef short bf16x8 __attribute__((ext_vector_type(8)));
typedef float f32x4 __attribute__((ext_vector_type(4)));
typedef unsigned short us4 __attribute__((ext_vector_type(4)));

__device__ __forceinline__ unsigned short f2bf(float f){
    unsigned int u = __builtin_bit_cast(unsigned int, f);
    u += 0x7fffu + ((u >> 16) & 1u);   // round-to-nearest-even
    return (unsigned short)(u >> 16);
}
__device__ __forceinline__ float bf2f(unsigned short h){
    unsigned int u = ((unsigned int)h) << 16;
    return __builtin_bit_cast(float, u);
}
__device__ __forceinline__ void gload_lds16(const void* g, void* l){
    __builtin_amdgcn_global_load_lds(
        (const __attribute__((address_space(1))) unsigned int*)g,
        (__attribute__((address_space(3))) unsigned int*)l, 16, 0, 0);
}

// ---- prep: x (B,C,HW) f32  ->  xbT (B,HW,C) bf16 (transpose + convert) ----
__global__ __launch_bounds__(256) void k_prep_x(const float* __restrict__ x,
                                                unsigned short* __restrict__ xbT){
    __shared__ float tile[32][33];
    int b  = blockIdx.z;
    int c0 = blockIdx.y * 32;
    int n0 = blockIdx.x * 32;
    int tx = threadIdx.x & 31;
    int ty = threadIdx.x >> 5;   // 0..7
    const float* xp = x + (size_t)b * C_N * HW_N;
    #pragma unroll
    for (int i = 0; i < 4; ++i)
        tile[ty + 8*i][tx] = xp[(size_t)(c0 + ty + 8*i) * HW_N + n0 + tx];
    __syncthreads();
    unsigned short* op = xbT + (size_t)b * HW_N * C_N;
    #pragma unroll
    for (int i = 0; i < 4; ++i)
        op[(size_t)(n0 + ty + 8*i) * C_N + c0 + tx] = f2bf(tile[tx][ty + 8*i]);
}

// ---- prep: Wcat = [theta_w; phi_w] -> bf16 (1024x1024), bias concat, w1 bf16
__global__ __launch_bounds__(256) void k_prep_w(const float* __restrict__ tw, const float* __restrict__ tb,
                                                const float* __restrict__ pw, const float* __restrict__ pb,
                                                const float* __restrict__ m1w,
                                                unsigned short* __restrict__ Wc, float* __restrict__ bias,
                                                unsigned short* __restrict__ w1b){
    int i = blockIdx.x * 256 + threadIdx.x;    // over 1024*1024
    int o = i >> 10, c = i & 1023;
    float v = (o < 512) ? tw[(size_t)o * 1024 + c] : pw[(size_t)(o - 512) * 1024 + c];
    Wc[i] = f2bf(v);
    if (i < 1024) bias[i] = (i < 512) ? tb[i] : pb[i - 512];
    if (i < 64 * HW_N) w1b[i] = f2bf(m1w[i]);
}

// ---- GEMM1 (m97-style, BK=64): TPt[n][o] = bias[o] + sum_c Wc[o][c]*xbT[n][c]
// M=24576, N=1024, K=1024. BM=BN=128, BK=64. grid 1536: o-tile = bid&7.
// global_load_lds w16, LINEAR LDS dest; swizzle on global source + ds_read
// (rule 21). Row stride 128B; unit ^= (row&7) -> 2-way bank alias (free).
// __launch_bounds__(256,3): target 3 waves/SIMD (VGPR+AGPR <= ~170).
__global__ __launch_bounds__(256, 3) void k_gemm1(const unsigned short* __restrict__ Wc,
                                               const float* __restrict__ bias,
                                               const unsigned short* __restrict__ xbT,
                                               unsigned short* __restrict__ TPt,
                                               float2* __restrict__ part){
    __shared__ __align__(16) unsigned short lW[128 * 64];  // 16KB, rows = o
    __shared__ __align__(16) unsigned short lX[128 * 64];  // 16KB, rows = n
    int bid = blockIdx.x;
    int nb = bid & 7;        // o-tile (0..7)  -> pins Wc panel per XCD L2
    int mb = bid >> 3;       // n-tile (0..191)
    int tid = threadIdx.x, lane = tid & 63, wave = tid >> 6;
    int wr = wave >> 1, wc = wave & 1;
    int fr = lane & 15, fg = lane >> 4;

    const unsigned short* Wg = Wc  + (size_t)(nb * 128) * C_N;
    const unsigned short* Xg = xbT + (size_t)(mb * 128) * C_N;

    // staging: unit u = tid + 256*i; row = u>>3 (= tid>>3 + 32i), subunit = tid&7
    int row0 = tid >> 3;                 // 0..31
    int su   = tid & 7;
    int gsw  = (su ^ (row0 & 7)) * 8;    // pre-swizzled global col (elems); (row&7) indep of i
    const unsigned short* wsrc = Wg + (size_t)row0 * C_N + gsw;
    const unsigned short* xsrc = Xg + (size_t)row0 * C_N + gsw;

    f32x4 acc[4][4];
    f32x4 zero = {0.f, 0.f, 0.f, 0.f};
    #pragma unroll
    for (int i = 0; i < 4; ++i)
        #pragma unroll
        for (int j = 0; j < 4; ++j)
            acc[i][j] = zero;

    for (int k0 = 0; k0 < C_N; k0 += 64){
        __syncthreads();
        #pragma unroll
        for (int i = 0; i < 4; ++i){
            gload_lds16(wsrc + (size_t)(32 * i) * C_N + k0, (char*)lW + tid * 16 + i * 4096);
            gload_lds16(xsrc + (size_t)(32 * i) * C_N + k0, (char*)lX + tid * 16 + i * 4096);
        }
        __syncthreads();   // compiler drains vmcnt(0) here (m97 structure)

        #pragma unroll
        for (int kk = 0; kk < 2; ++kk){
            bf16x8 wf[4], xf[4];
            #pragma unroll
            for (int j = 0; j < 4; ++j){
                int row = wc * 64 + j * 16 + fr;
                int un  = (kk * 4 + fg) ^ (row & 7);
                wf[j] = *(const bf16x8*)((char*)lW + row * 128 + un * 16);
            }
            #pragma unroll
            for (int i = 0; i < 4; ++i){
                int row = wr * 64 + i * 16 + fr;
                int un  = (kk * 4 + fg) ^ (row & 7);
                xf[i] = *(const bf16x8*)((char*)lX + row * 128 + un * 16);
            }
            #pragma unroll
            for (int i = 0; i < 4; ++i)
                #pragma unroll
                for (int j = 0; j < 4; ++j)
                    acc[i][j] = __builtin_amdgcn_mfma_f32_16x16x32_bf16(wf[j], xf[i], acc[i][j], 0, 0, 0);
        }
    }

    // epilogue: D[row=o (fg*4+r within frag j), col=n (fr within frag i)]
    float s[4] = {0.f,0.f,0.f,0.f}, q[4] = {0.f,0.f,0.f,0.f};
    #pragma unroll
    for (int i = 0; i < 4; ++i){
        int n = mb * 128 + wr * 64 + i * 16 + fr;
        #pragma unroll
        for (int j = 0; j < 4; ++j){
            int o0 = nb * 128 + wc * 64 + j * 16 + fg * 4;
            float4 b4 = *(const float4*)(bias + o0);
            float v0 = acc[i][j][0] + b4.x;
            float v1 = acc[i][j][1] + b4.y;
            float v2 = acc[i][j][2] + b4.z;
            float v3 = acc[i][j][3] + b4.w;
            s[i] += v0 + v1 + v2 + v3;
            q[i] += v0*v0 + v1*v1 + v2*v2 + v3*v3;
            us4 pk;
            pk[0] = f2bf(v0); pk[1] = f2bf(v1); pk[2] = f2bf(v2); pk[3] = f2bf(v3);
            *(us4*)(TPt + (size_t)n * 1024 + o0) = pk;
        }
    }
    // reduce across the 4 fg groups (lanes fr, fr+16, fr+32, fr+48)
    #pragma unroll
    for (int i = 0; i < 4; ++i){
        s[i] += __shfl_xor(s[i], 16); s[i] += __shfl_xor(s[i], 32);
        q[i] += __shfl_xor(q[i], 16); q[i] += __shfl_xor(q[i], 32);
    }
    if (lane < 16){   // fg == 0
        int chunk = nb * 2 + wc;   // 64-col chunk index (0..15)
        #pragma unroll
        for (int i = 0; i < 4; ++i){
            int n = mb * 128 + wr * 64 + i * 16 + fr;
            part[(size_t)n * 16 + chunk] = make_float2(s[i], q[i]);
        }
    }
}

// ---- fold partials -> per-(row, half) mean & 1/(std+eps), ddof=1 ----------
__global__ __launch_bounds__(256) void k_stats(const float2* __restrict__ part,
                                               float2* __restrict__ stats){
    int idx = blockIdx.x * 256 + threadIdx.x;   // over MROWS*2, exact
    int n = idx >> 1, h = idx & 1;
    const float2* p = part + (size_t)n * 16 + h * 8;
    float S = 0.f, Q = 0.f;
    #pragma unroll
    for (int k = 0; k < 8; ++k){ float2 v = p[k]; S += v.x; Q += v.y; }
    float mean = S * (1.f / 512.f);
    float var  = (Q - 512.f * mean * mean) * (1.f / 511.f);
    float inv  = 1.f / (sqrtf(fmaxf(var, 0.f)) + 1e-4f);
    stats[idx] = make_float2(mean, inv);
}

// ---- GEMM2 with fused z-score: F[b][n][m] = (ThN[n]·PhN[m])/512 -----------
__global__ __launch_bounds__(256) void k_gemm2(const unsigned short* __restrict__ TPt,
                                               const float2* __restrict__ stats,
                                               unsigned short* __restrict__ F){
    __shared__ __align__(16) unsigned short lT[64 * 32];  // theta rows (n)
    __shared__ __align__(16) unsigned short lP[64 * 32];  // phi rows (m)
    int b   = blockIdx.z;
    int tn  = blockIdx.y;   // theta 64-row panel
    int tm  = blockIdx.x;   // phi 64-row panel
    int tid = threadIdx.x, lane = tid & 63, wave = tid >> 6;
    int wr = wave >> 1, wc = wave & 1;
    int fr = lane & 15, fg = lane >> 4;

    int sr = tid >> 2;                       // 0..63 staged row
    int su = tid & 3;                        // 16B unit
    int swu = (su ^ ((sr >> 1) & 3)) * 16;   // swizzled LDS byte offset of unit
    int gn = b * HW_N + tn * 64 + sr;        // theta global row
    int gm = b * HW_N + tm * 64 + sr;        // phi global row
    float2 stT = stats[(size_t)gn * 2 + 0];
    float2 stP = stats[(size_t)gm * 2 + 1];

    f32x4 acc[2][2];
    f32x4 zero = {0.f, 0.f, 0.f, 0.f};
    #pragma unroll
    for (int i = 0; i < 2; ++i)
        #pragma unroll
        for (int j = 0; j < 2; ++j)
            acc[i][j] = zero;

    for (int k0 = 0; k0 < CI_N; k0 += 32){
        bf16x8 vt = *(const bf16x8*)(TPt + (size_t)gn * 1024 + k0 + su * 8);
        bf16x8 vp = *(const bf16x8*)(TPt + (size_t)gm * 1024 + 512 + k0 + su * 8);
        bf16x8 nt, np;
        #pragma unroll
        for (int e = 0; e < 8; ++e){
            nt[e] = (short)f2bf((bf2f((unsigned short)vt[e]) - stT.x) * stT.y);
            np[e] = (short)f2bf((bf2f((unsigned short)vp[e]) - stP.x) * stP.y);
        }
        __syncthreads();
        *(bf16x8*)((char*)lT + sr * 64 + swu) = nt;
        *(bf16x8*)((char*)lP + sr * 64 + swu) = np;
        __syncthreads();

        bf16x8 tf[2], pf[2];
        #pragma unroll
        for (int i = 0; i < 2; ++i){
            int row = wr * 32 + i * 16 + fr;
            tf[i] = *(const bf16x8*)((char*)lT + row * 64 + ((fg ^ ((row >> 1) & 3)) * 16));
        }
        #pragma unroll
        for (int j = 0; j < 2; ++j){
            int row = wc * 32 + j * 16 + fr;
            pf[j] = *(const bf16x8*)((char*)lP + row * 64 + ((fg ^ ((row >> 1) & 3)) * 16));
        }
        #pragma unroll
        for (int i = 0; i < 2; ++i)
            #pragma unroll
            for (int j = 0; j < 2; ++j)
                acc[i][j] = __builtin_amdgcn_mfma_f32_16x16x32_bf16(pf[j], tf[i], acc[i][j], 0, 0, 0);
    }

    // D[row=m (fg*4+r within frag j), col=n (fr within frag i)] -> F[n][m] us4
    #pragma unroll
    for (int i = 0; i < 2; ++i){
        int n = tn * 64 + wr * 32 + i * 16 + fr;
        #pragma unroll
        for (int j = 0; j < 2; ++j){
            int m0 = tm * 64 + wc * 32 + j * 16 + fg * 4;
            us4 pk;
            #pragma unroll
            for (int r = 0; r < 4; ++r)
                pk[r] = f2bf(acc[i][j][r] * (1.0f / 512.0f));
            *(us4*)(F + ((size_t)b * HW_N + n) * HW_N + m0) = pk;
        }
    }
}

// ---- mask head via MFMA: y[row] = sigmoid(w2·relu(BN(w1·Frow + m1b))) -----
__global__ __launch_bounds__(256) void k_mask2(const unsigned short* __restrict__ F,
        const unsigned short* __restrict__ w1b, const float* __restrict__ m1b,
        const float* __restrict__ bng, const float* __restrict__ bnb,
        const float* __restrict__ bnm, const float* __restrict__ bnv,
        const float* __restrict__ m2w, const float* __restrict__ m2b,
        float* __restrict__ mask){
    int tid = threadIdx.x, lane = tid & 63, wave = tid >> 6;
    int fr = lane & 15, fg = lane >> 4;
    int row0 = blockIdx.x * 64 + wave * 16;        // 16 rows per wave
    const unsigned short* Ag = F + (size_t)row0 * HW_N;

    f32x4 acc[4];
    f32x4 zero = {0.f, 0.f, 0.f, 0.f};
    #pragma unroll
    for (int j = 0; j < 4; ++j) acc[j] = zero;

    #pragma unroll
    for (int kk = 0; kk < 6; ++kk){
        bf16x8 af = *(const bf16x8*)(Ag + (size_t)fr * HW_N + kk * 32 + fg * 8);
        #pragma unroll
        for (int j = 0; j < 4; ++j){
            bf16x8 bfv = *(const bf16x8*)(w1b + (size_t)(j * 16 + fr) * HW_N + kk * 32 + fg * 8);
            acc[j] = __builtin_amdgcn_mfma_f32_16x16x32_bf16(af, bfv, acc[j], 0, 0, 0);
        }
    }

    float sc[4], sh[4], bb[4], w2v[4];
    #pragma unroll
    for (int j = 0; j < 4; ++j){
        int o = j * 16 + fr;
        float s = bng[o] * rsqrtf(bnv[o] + 1e-5f);
        sc[j] = s;
        sh[j] = bnb[o] - bnm[o] * s;
        bb[j] = m1b[o];
        w2v[j] = m2w[o];
    }
    float mb2 = m2b[0];

    #pragma unroll
    for (int r = 0; r < 4; ++r){
        float y = 0.f;
        #pragma unroll
        for (int j = 0; j < 4; ++j){
            float t = fmaxf((acc[j][r] + bb[j]) * sc[j] + sh[j], 0.f);
            y += t * w2v[j];
        }
        y += __shfl_xor(y, 1);
        y += __shfl_xor(y, 2);
        y += __shfl_xor(y, 4);
        y += __shfl_xor(y, 8);
        if (fr == 0)
            mask[row0 + fg * 4 + r] = 1.f / (1.f + __expf(-(y + mb2)));
    }
}

// ---- apply: out = x * (1 + mask) ------------------------------------------
__global__ __launch_bounds__(256) void k_apply(const float* __restrict__ x,
                                               const float* __restrict__ mask,
                                               float* __restrict__ out){
    size_t i4 = (size_t)blockIdx.x * 256 + threadIdx.x;
    size_t e  = i4 * 4;
    float4 v = ((const float4*)x)[i4];
    size_t n = e % HW_N;                        // 192 % 4 == 0: same row for all 4
    size_t b = e / ((size_t)C_N * HW_N);
    const float* mk = mask + b * HW_N + n;
    float4 o;
    o.x = v.x * (1.f + mk[0]);
    o.y = v.y * (1.f + mk[1]);
    o.z = v.z * (1.f + mk[2]);
    o.w = v.w * (1.f + mk[3]);
    ((float4*)out)[i4] = o;
}

extern "C" void kernel_launch(void* const* d_in, const int* in_sizes, int n_in,
                              void* d_out, int out_size, void* d_ws, size_t ws_size,
                              hipStream_t stream){
    (void)in_sizes; (void)n_in; (void)out_size; (void)ws_size;
    const float* x   = (const float*)d_in[0];
    const float* tw  = (const float*)d_in[1];
    const float* tb  = (const float*)d_in[2];
    const float* pw  = (const float*)d_in[3];
    const float* pb  = (const float*)d_in[4];
    const float* m1w = (const float*)d_in[5];
    const float* m1b = (const float*)d_in[6];
    const float* bng = (const float*)d_in[7];
    const float* bnb = (const float*)d_in[8];
    const float* bnm = (const float*)d_in[9];
    const float* bnv = (const float*)d_in[10];
    const float* m2w = (const float*)d_in[11];
    const float* m2b = (const float*)d_in[12];
    float* out = (float*)d_out;

    char* ws = (char*)d_ws;
    size_t off = 0;
    unsigned short* xbT = (unsigned short*)(ws + off); off += (size_t)MROWS * C_N * 2;        // 48 MB
    unsigned short* Wc  = (unsigned short*)(ws + off); off += (size_t)1024 * 1024 * 2;        // 2 MB
    float* bias         = (float*)(ws + off);          off += 4096;
    unsigned short* TPt = (unsigned short*)(ws + off); off += (size_t)MROWS * 1024 * 2;       // 48 MB
    unsigned short* F   = (unsigned short*)(ws + off); off += (size_t)MROWS * HW_N * 2;       // 9 MB
    float* mask         = (float*)(ws + off);          off += (size_t)MROWS * 4;
    unsigned short* w1b = (unsigned short*)(ws + off); off += (size_t)64 * HW_N * 2;
    off = (off + 255) & ~(size_t)255;
    float2* part        = (float2*)(ws + off);         off += (size_t)MROWS * 16 * 8;         // 3 MB
    float2* stats       = (float2*)(ws + off);         off += (size_t)MROWS * 2 * 8;          // 0.4 MB

    k_prep_x<<<dim3(6, 32, B_N), 256, 0, stream>>>(x, xbT);
    k_prep_w<<<dim3(4096), 256, 0, stream>>>(tw, tb, pw, pb, m1w, Wc, bias, w1b);
    k_gemm1<<<dim3(1536), 256, 0, stream>>>(Wc, bias, xbT, TPt, part);
    k_stats<<<dim3(MROWS * 2 / 256), 256, 0, stream>>>(part, stats);
    k_gemm2<<<dim3(3, 3, B_N), 256, 0, stream>>>(TPt, stats, F);
    k_mask2<<<dim3(MROWS / 64), 256, 0, stream>>>(F, w1b, m1b, bng, bnb, bnm, bnv, m2w, m2b, mask);
    k_apply<<<dim3(MROWS * C_N / 4 / 256), 256, 0, stream>>>(x, mask, out);
}

// Round 5
// 164.811 us; speedup vs baseline: 1.9542x; 1.0657x over previous
//
#include <hip/hip_runtime.h>

#define B_N 128
#define C_N 1024
#define HW_N 192
#define CI_N 512
#define MROWS (B_N * HW_N)   // 24576 flat rows

typedef short bf16x8 __attribute__((ext_vector_type(8)));
typedef float f32x4 __attribute__((ext_vector_type(4)));
typedef unsigned short us4 __attribute__((ext_vector_type(4)));
typedef unsigned short us8 __attribute__((ext_vector_type(8)));

__device__ __forceinline__ unsigned short f2bf(float f){
    unsigned int u = __builtin_bit_cast(unsigned int, f);
    u += 0x7fffu + ((u >> 16) & 1u);   // round-to-nearest-even
    return (unsigned short)(u >> 16);
}
__device__ __forceinline__ float bf2f(unsigned short h){
    unsigned int u = ((unsigned int)h) << 16;
    return __builtin_bit_cast(float, u);
}
__device__ __forceinline__ void gload_lds16(const void* g, void* l){
    __builtin_amdgcn_global_load_lds(
        (const __attribute__((address_space(1))) unsigned int*)g,
        (__attribute__((address_space(3))) unsigned int*)l, 16, 0, 0);
}

// ---- prep: x (B,C,HW) f32  ->  xbT (B,HW,C) bf16 (transpose + convert) ----
// 64c x 32n tile; float4 reads, us8 (16B) writes. LDS stride 37 (<=2-way).
__global__ __launch_bounds__(256) void k_prep_x(const float* __restrict__ x,
                                                unsigned short* __restrict__ xbT){
    __shared__ float tile[64][37];
    int b  = blockIdx.z;
    int c0 = blockIdx.y * 64;
    int n0 = blockIdx.x * 32;
    int t  = threadIdx.x;
    const float* xp = x + (size_t)b * C_N * HW_N;
    int cr = t >> 3;          // 0..31
    int nw = (t & 7) * 4;     // 0..28
    #pragma unroll
    for (int i = 0; i < 2; ++i){
        float4 v = *(const float4*)(xp + (size_t)(c0 + cr + 32 * i) * HW_N + n0 + nw);
        tile[cr + 32 * i][nw + 0] = v.x;
        tile[cr + 32 * i][nw + 1] = v.y;
        tile[cr + 32 * i][nw + 2] = v.z;
        tile[cr + 32 * i][nw + 3] = v.w;
    }
    __syncthreads();
    int nl = t >> 3;          // 0..31 output row (n)
    int j  = t & 7;           // 8-elem c group
    us8 pk;
    #pragma unroll
    for (int e = 0; e < 8; ++e)
        pk[e] = f2bf(tile[j * 8 + e][nl]);
    *(us8*)(xbT + (size_t)(b * HW_N + n0 + nl) * C_N + c0 + j * 8) = pk;
}

// ---- prep: Wcat = [theta_w; phi_w] -> bf16 (1024x1024), bias concat, w1 bf16
__global__ __launch_bounds__(256) void k_prep_w(const float* __restrict__ tw, const float* __restrict__ tb,
                                                const float* __restrict__ pw, const float* __restrict__ pb,
                                                const float* __restrict__ m1w,
                                                unsigned short* __restrict__ Wc, float* __restrict__ bias,
                                                unsigned short* __restrict__ w1b){
    int i = blockIdx.x * 256 + threadIdx.x;    // over 1024*1024
    int o = i >> 10, c = i & 1023;
    float v = (o < 512) ? tw[(size_t)o * 1024 + c] : pw[(size_t)(o - 512) * 1024 + c];
    Wc[i] = f2bf(v);
    if (i < 1024) bias[i] = (i < 512) ? tb[i] : pb[i - 512];
    if (i < 64 * HW_N) w1b[i] = f2bf(m1w[i]);
}

// ---- GEMM1 (m97-style, BK=64, XCD-swizzled): TPt[n][o] = bias[o] + Wc·xbT -
// grid 1536: xcd = bid&7, slot = bid>>3; n-tile = xcd*24 + slot/8, o-tile =
// slot&7 -> the 8 blocks sharing an xbT panel run consecutively on ONE XCD
// (panel L2-resident), Wc (2MB) L2-resident per XCD.
__global__ __launch_bounds__(256, 3) void k_gemm1(const unsigned short* __restrict__ Wc,
                                               const float* __restrict__ bias,
                                               const unsigned short* __restrict__ xbT,
                                               unsigned short* __restrict__ TPt,
                                               float2* __restrict__ part){
    __shared__ __align__(16) unsigned short lW[128 * 64];  // 16KB, rows = o
    __shared__ __align__(16) unsigned short lX[128 * 64];  // 16KB, rows = n
    int bid  = blockIdx.x;
    int xcd  = bid & 7;
    int slot = bid >> 3;
    int mb = xcd * 24 + (slot >> 3);   // n-tile (0..191)
    int nb = slot & 7;                 // o-tile (0..7)
    int tid = threadIdx.x, lane = tid & 63, wave = tid >> 6;
    int wr = wave >> 1, wc = wave & 1;
    int fr = lane & 15, fg = lane >> 4;

    const unsigned short* Wg = Wc  + (size_t)(nb * 128) * C_N;
    const unsigned short* Xg = xbT + (size_t)(mb * 128) * C_N;

    // staging: unit u = tid + 256*i; row = u>>3 (= tid>>3 + 32i), subunit = tid&7
    int row0 = tid >> 3;                 // 0..31
    int su   = tid & 7;
    int gsw  = (su ^ (row0 & 7)) * 8;    // pre-swizzled global col (elems)
    const unsigned short* wsrc = Wg + (size_t)row0 * C_N + gsw;
    const unsigned short* xsrc = Xg + (size_t)row0 * C_N + gsw;

    f32x4 acc[4][4];
    f32x4 zero = {0.f, 0.f, 0.f, 0.f};
    #pragma unroll
    for (int i = 0; i < 4; ++i)
        #pragma unroll
        for (int j = 0; j < 4; ++j)
            acc[i][j] = zero;

    for (int k0 = 0; k0 < C_N; k0 += 64){
        __syncthreads();
        #pragma unroll
        for (int i = 0; i < 4; ++i){
            gload_lds16(wsrc + (size_t)(32 * i) * C_N + k0, (char*)lW + tid * 16 + i * 4096);
            gload_lds16(xsrc + (size_t)(32 * i) * C_N + k0, (char*)lX + tid * 16 + i * 4096);
        }
        __syncthreads();   // compiler drains vmcnt(0) here (m97 structure)

        #pragma unroll
        for (int kk = 0; kk < 2; ++kk){
            bf16x8 wf[4], xf[4];
            #pragma unroll
            for (int j = 0; j < 4; ++j){
                int row = wc * 64 + j * 16 + fr;
                int un  = (kk * 4 + fg) ^ (row & 7);
                wf[j] = *(const bf16x8*)((char*)lW + row * 128 + un * 16);
            }
            #pragma unroll
            for (int i = 0; i < 4; ++i){
                int row = wr * 64 + i * 16 + fr;
                int un  = (kk * 4 + fg) ^ (row & 7);
                xf[i] = *(const bf16x8*)((char*)lX + row * 128 + un * 16);
            }
            #pragma unroll
            for (int i = 0; i < 4; ++i)
                #pragma unroll
                for (int j = 0; j < 4; ++j)
                    acc[i][j] = __builtin_amdgcn_mfma_f32_16x16x32_bf16(wf[j], xf[i], acc[i][j], 0, 0, 0);
        }
    }

    // epilogue: D[row=o (fg*4+r within frag j), col=n (fr within frag i)]
    float s[4] = {0.f,0.f,0.f,0.f}, q[4] = {0.f,0.f,0.f,0.f};
    #pragma unroll
    for (int i = 0; i < 4; ++i){
        int n = mb * 128 + wr * 64 + i * 16 + fr;
        #pragma unroll
        for (int j = 0; j < 4; ++j){
            int o0 = nb * 128 + wc * 64 + j * 16 + fg * 4;
            float4 b4 = *(const float4*)(bias + o0);
            float v0 = acc[i][j][0] + b4.x;
            float v1 = acc[i][j][1] + b4.y;
            float v2 = acc[i][j][2] + b4.z;
            float v3 = acc[i][j][3] + b4.w;
            s[i] += v0 + v1 + v2 + v3;
            q[i] += v0*v0 + v1*v1 + v2*v2 + v3*v3;
            us4 pk;
            pk[0] = f2bf(v0); pk[1] = f2bf(v1); pk[2] = f2bf(v2); pk[3] = f2bf(v3);
            *(us4*)(TPt + (size_t)n * 1024 + o0) = pk;
        }
    }
    // reduce across the 4 fg groups (lanes fr, fr+16, fr+32, fr+48)
    #pragma unroll
    for (int i = 0; i < 4; ++i){
        s[i] += __shfl_xor(s[i], 16); s[i] += __shfl_xor(s[i], 32);
        q[i] += __shfl_xor(q[i], 16); q[i] += __shfl_xor(q[i], 32);
    }
    if (lane < 16){   // fg == 0
        int chunk = nb * 2 + wc;   // 64-col chunk index (0..15)
        #pragma unroll
        for (int i = 0; i < 4; ++i){
            int n = mb * 128 + wr * 64 + i * 16 + fr;
            part[(size_t)n * 16 + chunk] = make_float2(s[i], q[i]);
        }
    }
}

// ---- fold partials -> per-(row, half) mean & 1/(std+eps), ddof=1 ----------
__global__ __launch_bounds__(256) void k_stats(const float2* __restrict__ part,
                                               float2* __restrict__ stats){
    int idx = blockIdx.x * 256 + threadIdx.x;   // over MROWS*2, exact
    int n = idx >> 1, h = idx & 1;
    const float2* p = part + (size_t)n * 16 + h * 8;
    float S = 0.f, Q = 0.f;
    #pragma unroll
    for (int k = 0; k < 8; ++k){ float2 v = p[k]; S += v.x; Q += v.y; }
    float mean = S * (1.f / 512.f);
    float var  = (Q - 512.f * mean * mean) * (1.f / 511.f);
    float inv  = 1.f / (sqrtf(fmaxf(var, 0.f)) + 1e-4f);
    stats[idx] = make_float2(mean, inv);
}

// ---- GEMM2 with fused z-score, BK=64: F[b][n][m] = (ThN[n]·PhN[m])/512 ----
__global__ __launch_bounds__(256) void k_gemm2(const unsigned short* __restrict__ TPt,
                                               const float2* __restrict__ stats,
                                               unsigned short* __restrict__ F){
    __shared__ __align__(16) unsigned short lT[64 * 64];  // 8KB theta rows (n)
    __shared__ __align__(16) unsigned short lP[64 * 64];  // 8KB phi rows (m)
    int b   = blockIdx.z;
    int tn  = blockIdx.y;   // theta 64-row panel
    int tm  = blockIdx.x;   // phi 64-row panel
    int tid = threadIdx.x, lane = tid & 63, wave = tid >> 6;
    int wr = wave >> 1, wc = wave & 1;
    int fr = lane & 15, fg = lane >> 4;

    int r0 = tid >> 3;                       // 0..31 staged row (and r0+32)
    int su = tid & 7;                        // 16B unit within 128B row
    int sw0 = r0 * 128 + ((su ^ (r0 & 7)) * 16);          // (r0+32)&7 == r0&7
    int sw1 = (r0 + 32) * 128 + ((su ^ (r0 & 7)) * 16);
    int gn0 = b * HW_N + tn * 64 + r0, gn1 = gn0 + 32;
    int gm0 = b * HW_N + tm * 64 + r0, gm1 = gm0 + 32;
    float2 sT0 = stats[(size_t)gn0 * 2 + 0], sT1 = stats[(size_t)gn1 * 2 + 0];
    float2 sP0 = stats[(size_t)gm0 * 2 + 1], sP1 = stats[(size_t)gm1 * 2 + 1];

    f32x4 acc[2][2];
    f32x4 zero = {0.f, 0.f, 0.f, 0.f};
    #pragma unroll
    for (int i = 0; i < 2; ++i)
        #pragma unroll
        for (int j = 0; j < 2; ++j)
            acc[i][j] = zero;

    for (int k0 = 0; k0 < CI_N; k0 += 64){
        bf16x8 vt0 = *(const bf16x8*)(TPt + (size_t)gn0 * 1024 + k0 + su * 8);
        bf16x8 vt1 = *(const bf16x8*)(TPt + (size_t)gn1 * 1024 + k0 + su * 8);
        bf16x8 vp0 = *(const bf16x8*)(TPt + (size_t)gm0 * 1024 + 512 + k0 + su * 8);
        bf16x8 vp1 = *(const bf16x8*)(TPt + (size_t)gm1 * 1024 + 512 + k0 + su * 8);
        bf16x8 nt0, nt1, np0, np1;
        #pragma unroll
        for (int e = 0; e < 8; ++e){
            nt0[e] = (short)f2bf((bf2f((unsigned short)vt0[e]) - sT0.x) * sT0.y);
            nt1[e] = (short)f2bf((bf2f((unsigned short)vt1[e]) - sT1.x) * sT1.y);
            np0[e] = (short)f2bf((bf2f((unsigned short)vp0[e]) - sP0.x) * sP0.y);
            np1[e] = (short)f2bf((bf2f((unsigned short)vp1[e]) - sP1.x) * sP1.y);
        }
        __syncthreads();
        *(bf16x8*)((char*)lT + sw0) = nt0;
        *(bf16x8*)((char*)lT + sw1) = nt1;
        *(bf16x8*)((char*)lP + sw0) = np0;
        *(bf16x8*)((char*)lP + sw1) = np1;
        __syncthreads();

        #pragma unroll
        for (int kk = 0; kk < 2; ++kk){
            bf16x8 tf[2], pf[2];
            #pragma unroll
            for (int i = 0; i < 2; ++i){
                int row = wr * 32 + i * 16 + fr;
                int un  = (kk * 4 + fg) ^ (row & 7);
                tf[i] = *(const bf16x8*)((char*)lT + row * 128 + un * 16);
            }
            #pragma unroll
            for (int j = 0; j < 2; ++j){
                int row = wc * 32 + j * 16 + fr;
                int un  = (kk * 4 + fg) ^ (row & 7);
                pf[j] = *(const bf16x8*)((char*)lP + row * 128 + un * 16);
            }
            #pragma unroll
            for (int i = 0; i < 2; ++i)
                #pragma unroll
                for (int j = 0; j < 2; ++j)
                    acc[i][j] = __builtin_amdgcn_mfma_f32_16x16x32_bf16(pf[j], tf[i], acc[i][j], 0, 0, 0);
        }
    }

    // D[row=m (fg*4+r within frag j), col=n (fr within frag i)] -> F[n][m] us4
    #pragma unroll
    for (int i = 0; i < 2; ++i){
        int n = tn * 64 + wr * 32 + i * 16 + fr;
        #pragma unroll
        for (int j = 0; j < 2; ++j){
            int m0 = tm * 64 + wc * 32 + j * 16 + fg * 4;
            us4 pk;
            #pragma unroll
            for (int r = 0; r < 4; ++r)
                pk[r] = f2bf(acc[i][j][r] * (1.0f / 512.0f));
            *(us4*)(F + ((size_t)b * HW_N + n) * HW_N + m0) = pk;
        }
    }
}

// ---- mask head via MFMA: y[row] = sigmoid(w2·relu(BN(w1·Frow + m1b))) -----
__global__ __launch_bounds__(256) void k_mask2(const unsigned short* __restrict__ F,
        const unsigned short* __restrict__ w1b, const float* __restrict__ m1b,
        const float* __restrict__ bng, const float* __restrict__ bnb,
        const float* __restrict__ bnm, const float* __restrict__ bnv,
        const float* __restrict__ m2w, const float* __restrict__ m2b,
        float* __restrict__ mask){
    int tid = threadIdx.x, lane = tid & 63, wave = tid >> 6;
    int fr = lane & 15, fg = lane >> 4;
    int row0 = blockIdx.x * 64 + wave * 16;        // 16 rows per wave
    const unsigned short* Ag = F + (size_t)row0 * HW_N;

    f32x4 acc[4];
    f32x4 zero = {0.f, 0.f, 0.f, 0.f};
    #pragma unroll
    for (int j = 0; j < 4; ++j) acc[j] = zero;

    #pragma unroll
    for (int kk = 0; kk < 6; ++kk){
        bf16x8 af = *(const bf16x8*)(Ag + (size_t)fr * HW_N + kk * 32 + fg * 8);
        #pragma unroll
        for (int j = 0; j < 4; ++j){
            bf16x8 bfv = *(const bf16x8*)(w1b + (size_t)(j * 16 + fr) * HW_N + kk * 32 + fg * 8);
            acc[j] = __builtin_amdgcn_mfma_f32_16x16x32_bf16(af, bfv, acc[j], 0, 0, 0);
        }
    }

    float sc[4], sh[4], bb[4], w2v[4];
    #pragma unroll
    for (int j = 0; j < 4; ++j){
        int o = j * 16 + fr;
        float s = bng[o] * rsqrtf(bnv[o] + 1e-5f);
        sc[j] = s;
        sh[j] = bnb[o] - bnm[o] * s;
        bb[j] = m1b[o];
        w2v[j] = m2w[o];
    }
    float mb2 = m2b[0];

    #pragma unroll
    for (int r = 0; r < 4; ++r){
        float y = 0.f;
        #pragma unroll
        for (int j = 0; j < 4; ++j){
            float t = fmaxf((acc[j][r] + bb[j]) * sc[j] + sh[j], 0.f);
            y += t * w2v[j];
        }
        y += __shfl_xor(y, 1);
        y += __shfl_xor(y, 2);
        y += __shfl_xor(y, 4);
        y += __shfl_xor(y, 8);
        if (fr == 0)
            mask[row0 + fg * 4 + r] = 1.f / (1.f + __expf(-(y + mb2)));
    }
}

// ---- apply: out = x * (1 + mask) ------------------------------------------
__global__ __launch_bounds__(256) void k_apply(const float* __restrict__ x,
                                               const float* __restrict__ mask,
                                               float* __restrict__ out){
    size_t i4 = (size_t)blockIdx.x * 256 + threadIdx.x;
    size_t e  = i4 * 4;
    float4 v = ((const float4*)x)[i4];
    size_t n = e % HW_N;                        // 192 % 4 == 0: same row for all 4
    size_t b = e / ((size_t)C_N * HW_N);
    const float* mk = mask + b * HW_N + n;
    float4 o;
    o.x = v.x * (1.f + mk[0]);
    o.y = v.y * (1.f + mk[1]);
    o.z = v.z * (1.f + mk[2]);
    o.w = v.w * (1.f + mk[3]);
    ((float4*)out)[i4] = o;
}

extern "C" void kernel_launch(void* const* d_in, const int* in_sizes, int n_in,
                              void* d_out, int out_size, void* d_ws, size_t ws_size,
                              hipStream_t stream){
    (void)in_sizes; (void)n_in; (void)out_size; (void)ws_size;
    const float* x   = (const float*)d_in[0];
    const float* tw  = (const float*)d_in[1];
    const float* tb  = (const float*)d_in[2];
    const float* pw  = (const float*)d_in[3];
    const float* pb  = (const float*)d_in[4];
    const float* m1w = (const float*)d_in[5];
    const float* m1b = (const float*)d_in[6];
    const float* bng = (const float*)d_in[7];
    const float* bnb = (const float*)d_in[8];
    const float* bnm = (const float*)d_in[9];
    const float* bnv = (const float*)d_in[10];
    const float* m2w = (const float*)d_in[11];
    const float* m2b = (const float*)d_in[12];
    float* out = (float*)d_out;

    char* ws = (char*)d_ws;
    size_t off = 0;
    unsigned short* xbT = (unsigned short*)(ws + off); off += (size_t)MROWS * C_N * 2;        // 48 MB
    unsigned short* Wc  = (unsigned short*)(ws + off); off += (size_t)1024 * 1024 * 2;        // 2 MB
    float* bias         = (float*)(ws + off);          off += 4096;
    unsigned short* TPt = (unsigned short*)(ws + off); off += (size_t)MROWS * 1024 * 2;       // 48 MB
    unsigned short* F   = (unsigned short*)(ws + off); off += (size_t)MROWS * HW_N * 2;       // 9 MB
    float* mask         = (float*)(ws + off);          off += (size_t)MROWS * 4;
    unsigned short* w1b = (unsigned short*)(ws + off); off += (size_t)64 * HW_N * 2;
    off = (off + 255) & ~(size_t)255;
    float2* part        = (float2*)(ws + off);         off += (size_t)MROWS * 16 * 8;         // 3 MB
    float2* stats       = (float2*)(ws + off);         off += (size_t)MROWS * 2 * 8;          // 0.4 MB

    k_prep_x<<<dim3(6, 16, B_N), 256, 0, stream>>>(x, xbT);
    k_prep_w<<<dim3(4096), 256, 0, stream>>>(tw, tb, pw, pb, m1w, Wc, bias, w1b);
    k_gemm1<<<dim3(1536), 256, 0, stream>>>(Wc, bias, xbT, TPt, part);
    k_stats<<<dim3(MROWS * 2 / 256), 256, 0, stream>>>(part, stats);
    k_gemm2<<<dim3(3, 3, B_N), 256, 0, stream>>>(TPt, stats, F);
    k_mask2<<<dim3(MROWS / 64), 256, 0, stream>>>(F, w1b, m1b, bng, bnb, bnm, bnv, m2w, m2b, mask);
    k_apply<<<dim3(MROWS * C_N / 4 / 256), 256, 0, stream>>>(x, mask, out);
}